// Round 1
// baseline (97.299 us; speedup 1.0000x reference)
//
#include <hip/hip_runtime.h>

// TinyQuantumClassifier: B independent 2-qubit real statevector sims.
// Memory-bound map: 12 B/sample traffic (8 read + 4 write), ~16 us roofline.
// 4 samples/thread -> 2x float4 loads + 1x float4 store per thread (16 B/lane).

__global__ __launch_bounds__(256) void tqc_kernel(
    const float4* __restrict__ feat,   // features viewed as float4; feat[2t], feat[2t+1] = 4 samples
    const float*  __restrict__ theta,  // 4 floats, uniform
    float4*       __restrict__ out,    // out[t] = 4 results
    int n4)                            // number of float4 outputs (B/4)
{
    int t = blockIdx.x * blockDim.x + threadIdx.x;
    if (t >= n4) return;

    // Uniform variational-layer rotations (hoisted; same for all samples).
    float ca0, sa0, cb0, sb0, ca1, sa1, cb1, sb1;
    __sincosf(0.5f * theta[0], &sa0, &ca0);  // layer 0, wire 0
    __sincosf(0.5f * theta[1], &sb0, &cb0);  // layer 0, wire 1
    __sincosf(0.5f * theta[2], &sa1, &ca1);  // layer 1, wire 0
    __sincosf(0.5f * theta[3], &sb1, &cb1);  // layer 1, wire 1

    float4 f0 = feat[2 * t];
    float4 f1 = feat[2 * t + 1];
    float xs[8] = {f0.x, f0.y, f0.z, f0.w, f1.x, f1.y, f1.z, f1.w};

    float res[4];
#pragma unroll
    for (int k = 0; k < 4; ++k) {
        // Encoding: state = (c0,s0) outer (c1,s1)
        float c0, s0, c1, s1;
        __sincosf(0.5f * xs[2 * k],     &s0, &c0);
        __sincosf(0.5f * xs[2 * k + 1], &s1, &c1);
        float a = c0 * c1;  // state[0][0]
        float b = c0 * s1;  // state[0][1]
        float c = s0 * c1;  // state[1][0]
        float d = s0 * s1;  // state[1][1]

        // Layer 0: RY(theta00) on wire0, RY(theta01) on wire1, CNOT(0,1)
        float na = ca0 * a - sa0 * c, nb = ca0 * b - sa0 * d;
        float nc = sa0 * a + ca0 * c, nd = sa0 * b + ca0 * d;
        a = cb0 * na - sb0 * nb;
        b = sb0 * na + cb0 * nb;
        float c2 = cb0 * nc - sb0 * nd;
        float d2 = sb0 * nc + cb0 * nd;
        c = d2;  // CNOT: state[1][:] reversed
        d = c2;

        // Layer 1
        na = ca1 * a - sa1 * c; nb = ca1 * b - sa1 * d;
        nc = sa1 * a + ca1 * c; nd = sa1 * b + ca1 * d;
        a = cb1 * na - sb1 * nb;
        b = sb1 * na + cb1 * nb;
        c2 = cb1 * nc - sb1 * nd;
        d2 = sb1 * nc + cb1 * nd;
        c = d2;
        d = c2;

        // <Z0> = P(wire0=0) - P(wire0=1)
        res[k] = a * a + b * b - c * c - d * d;
    }

    out[t] = make_float4(res[0], res[1], res[2], res[3]);
}

extern "C" void kernel_launch(void* const* d_in, const int* in_sizes, int n_in,
                              void* d_out, int out_size, void* d_ws, size_t ws_size,
                              hipStream_t stream) {
    const float* feat  = (const float*)d_in[0];  // [B,2] f32
    const float* theta = (const float*)d_in[1];  // [2,2] f32
    float* out = (float*)d_out;                  // [B,1] f32

    int b  = in_sizes[0] / 2;   // number of samples
    int n4 = b / 4;             // B divisible by 4 (8388608)
    int block = 256;
    int grid = (n4 + block - 1) / block;
    tqc_kernel<<<grid, block, 0, stream>>>(
        (const float4*)feat, theta, (float4*)out, n4);
}